// Round 1
// baseline (1963.693 us; speedup 1.0000x reference)
//
#include <hip/hip_runtime.h>

#define Bdim 2
#define Ldim 2048
#define Ddim 1024
#define Hdim 16
#define HDdim 64

// ---------------- QKV projection: C[m,n] = sum_k X[m,k] * W[n,k] -------------
// M = B*L = 4096, N = 1024, K = 1024, for each of wq/wk/wv (grid.z)
#define BM 64
#define BN 64
#define BK 16

__global__ __launch_bounds__(256) void qkv_gemm_kernel(
    const float* __restrict__ x,
    const float* __restrict__ wq,
    const float* __restrict__ wk,
    const float* __restrict__ wv,
    float* __restrict__ q_ws,
    float* __restrict__ kT_ws,
    float* __restrict__ v_ws)
{
    __shared__ float As[BK][BM + 4];   // [k][m], stride 68: float4-aligned, 2-way banks
    __shared__ float Bs[BK][BN + 4];   // [k][n]

    const int tid = threadIdx.x;
    const int tx = tid & 15;           // n-tile position
    const int ty = tid >> 4;           // m-tile position
    const int n0 = blockIdx.x * BN;
    const int m0 = blockIdx.y * BM;
    const int z  = blockIdx.z;

    const float* W = (z == 0) ? wq : (z == 1) ? wk : wv;

    const int lrow = tid >> 2;         // 0..63 (row within tile)
    const int lc4  = tid & 3;          // 0..3  (which float4 of the 16-wide k chunk)

    float acc[4][4];
    #pragma unroll
    for (int i = 0; i < 4; ++i)
        #pragma unroll
        for (int j = 0; j < 4; ++j) acc[i][j] = 0.f;

    for (int kt = 0; kt < Ddim; kt += BK) {
        float4 av = *reinterpret_cast<const float4*>(&x[(size_t)(m0 + lrow) * Ddim + kt + lc4 * 4]);
        float4 bv = *reinterpret_cast<const float4*>(&W[(size_t)(n0 + lrow) * Ddim + kt + lc4 * 4]);
        __syncthreads();               // protect previous iteration's reads
        As[lc4*4+0][lrow] = av.x; As[lc4*4+1][lrow] = av.y;
        As[lc4*4+2][lrow] = av.z; As[lc4*4+3][lrow] = av.w;
        Bs[lc4*4+0][lrow] = bv.x; Bs[lc4*4+1][lrow] = bv.y;
        Bs[lc4*4+2][lrow] = bv.z; Bs[lc4*4+3][lrow] = bv.w;
        __syncthreads();

        #pragma unroll
        for (int kk = 0; kk < BK; ++kk) {
            float4 a = *reinterpret_cast<const float4*>(&As[kk][ty*4]);  // broadcast
            float4 b = *reinterpret_cast<const float4*>(&Bs[kk][tx*4]);  // 2-way
            float ar[4] = {a.x, a.y, a.z, a.w};
            float br[4] = {b.x, b.y, b.z, b.w};
            #pragma unroll
            for (int i = 0; i < 4; ++i)
                #pragma unroll
                for (int j = 0; j < 4; ++j)
                    acc[i][j] += ar[i] * br[j];
        }
    }

    // Epilogue: scatter into attention-friendly layouts.
    // q,v: [bh][l][d]  ;  k: transposed [bh][d][l] so attn K-reads are coalesced
    #pragma unroll
    for (int i = 0; i < 4; ++i) {
        const int m = m0 + ty*4 + i;
        const int b = m >> 11;               // / L
        const int l = m & (Ldim - 1);
        #pragma unroll
        for (int j = 0; j < 4; ++j) {
            const int n = n0 + tx*4 + j;
            const int h = n >> 6;            // / HD
            const int d = n & 63;
            const int bh = b * Hdim + h;
            const float val = acc[i][j];
            if (z == 0)      q_ws[((size_t)bh*Ldim + l)*HDdim + d] = val;
            else if (z == 1) kT_ws[((size_t)bh*HDdim + d)*Ldim + l] = val;
            else             v_ws[((size_t)bh*Ldim + l)*HDdim + d] = val;
        }
    }
}

// ---------------- Flash-style attention, fp32 -------------------------------
// One block = 16 q-rows of one (b,h). 4 waves, each owns 4 rows.
// KBLK = 64 keys staged per iteration.
__global__ __launch_bounds__(256) void attn_kernel(
    const float* __restrict__ q_ws,
    const float* __restrict__ kT_ws,
    const float* __restrict__ v_ws,
    const float* __restrict__ quantum,
    const float* __restrict__ scale,
    float* __restrict__ out)
{
    __shared__ float qs[16][64];       // broadcast reads
    __shared__ float Ks[64][65];       // [j][d], bank=(j+d)%32 -> 2-way (free)
    __shared__ float Vs[64][64];       // [j][d], read lane<->d conflict-free
    __shared__ float ps[4][4][64];     // [wave][row][key]

    const int tid  = threadIdx.x;
    const int lane = tid & 63;
    const int wave = tid >> 6;

    const int qt = blockIdx.x & 127;   // L/16 = 128 q-tiles
    const int bh = blockIdx.x >> 7;
    const int b  = bh >> 4;            // / H
    const int h  = bh & 15;
    const int q0 = qt * 16;

    const float sc = scale[h];

    // load Q tile: one float4 per thread
    {
        const int r = tid >> 4, d4 = tid & 15;
        *reinterpret_cast<float4*>(&qs[r][d4*4]) =
            *reinterpret_cast<const float4*>(&q_ws[((size_t)bh*Ldim + q0 + r)*HDdim + d4*4]);
    }

    const int r0 = wave * 4;
    float m_r[4], s_r[4], o_r[4];
    #pragma unroll
    for (int r = 0; r < 4; ++r) { m_r[r] = -1e30f; s_r[r] = 0.f; o_r[r] = 0.f; }

    for (int k0 = 0; k0 < Ldim; k0 += 64) {
        __syncthreads();   // previous iteration fully done with Ks/Vs
        #pragma unroll
        for (int i = 0; i < 4; ++i) {
            const int idx = tid + i*256;          // 0..1023
            const int dk = idx >> 4, j4 = idx & 15;
            float4 t = *reinterpret_cast<const float4*>(
                &kT_ws[((size_t)bh*HDdim + dk)*Ldim + k0 + j4*4]);
            Ks[j4*4+0][dk] = t.x; Ks[j4*4+1][dk] = t.y;
            Ks[j4*4+2][dk] = t.z; Ks[j4*4+3][dk] = t.w;
            *reinterpret_cast<float4*>(&Vs[dk][j4*4]) =
                *reinterpret_cast<const float4*>(
                    &v_ws[((size_t)bh*Ldim + k0 + dk)*HDdim + j4*4]);
        }
        __syncthreads();

        // QK^T: lane <-> key
        float a0 = 0.f, a1 = 0.f, a2 = 0.f, a3 = 0.f;
        #pragma unroll
        for (int d = 0; d < 64; ++d) {
            const float kd = Ks[lane][d];
            a0 += qs[r0+0][d] * kd;
            a1 += qs[r0+1][d] * kd;
            a2 += qs[r0+2][d] * kd;
            a3 += qs[r0+3][d] * kd;
        }
        const float accv[4] = {a0, a1, a2, a3};
        #pragma unroll
        for (int r = 0; r < 4; ++r) {
            float lg = (accv[r]*0.125f +
                        quantum[((size_t)b*Ldim + q0 + r0 + r)*Ldim + k0 + lane]) * sc;
            float mx = lg;
            #pragma unroll
            for (int off = 32; off > 0; off >>= 1) mx = fmaxf(mx, __shfl_xor(mx, off));
            const float newm = fmaxf(m_r[r], mx);
            const float p    = __expf(lg - newm);
            const float corr = __expf(m_r[r] - newm);
            float sump = p;
            #pragma unroll
            for (int off = 32; off > 0; off >>= 1) sump += __shfl_xor(sump, off);
            s_r[r] = s_r[r]*corr + sump;
            o_r[r] *= corr;
            m_r[r] = newm;
            ps[wave][r][lane] = p;
        }
        __syncthreads();   // ps visible (cross-lane via LDS)

        // PV: lane <-> d
        float b0 = 0.f, b1 = 0.f, b2 = 0.f, b3 = 0.f;
        #pragma unroll
        for (int j = 0; j < 64; ++j) {
            const float vj = Vs[j][lane];
            b0 += ps[wave][0][j] * vj;
            b1 += ps[wave][1][j] * vj;
            b2 += ps[wave][2][j] * vj;
            b3 += ps[wave][3][j] * vj;
        }
        o_r[0] += b0; o_r[1] += b1; o_r[2] += b2; o_r[3] += b3;
    }

    #pragma unroll
    for (int r = 0; r < 4; ++r) {
        const int l = q0 + r0 + r;
        out[((size_t)b*Ldim + l)*Ddim + h*HDdim + lane] = o_r[r] / s_r[r];
    }
}

extern "C" void kernel_launch(void* const* d_in, const int* in_sizes, int n_in,
                              void* d_out, int out_size, void* d_ws, size_t ws_size,
                              hipStream_t stream) {
    const float* x       = (const float*)d_in[0];
    const float* quantum = (const float*)d_in[1];
    const float* wq      = (const float*)d_in[2];
    const float* wk      = (const float*)d_in[3];
    const float* wv      = (const float*)d_in[4];
    const float* scale   = (const float*)d_in[5];
    float* out = (float*)d_out;

    const size_t per = (size_t)Bdim * Hdim * Ldim * HDdim;  // 4,194,304 floats
    float* q_ws  = (float*)d_ws;
    float* kT_ws = q_ws + per;
    float* v_ws  = kT_ws + per;

    dim3 g1(Ddim / BN, (Bdim * Ldim) / BM, 3);
    qkv_gemm_kernel<<<g1, 256, 0, stream>>>(x, wq, wk, wv, q_ws, kT_ws, v_ws);

    dim3 g2(Bdim * Hdim * (Ldim / 16));
    attn_kernel<<<g2, 256, 0, stream>>>(q_ws, kT_ws, v_ws, quantum, scale, out);
}

// Round 2
// 155.680 us; speedup vs baseline: 12.6136x; 12.6136x over previous
//
#include <hip/hip_runtime.h>

#define Bq 2
#define Lq 2048
#define Dq 1024
#define Hq 16
#define HDq 64

typedef _Float16 f16;
typedef _Float16 f16x8 __attribute__((ext_vector_type(8)));
typedef _Float16 f16x4 __attribute__((ext_vector_type(4)));
typedef float f32x4 __attribute__((ext_vector_type(4)));

__device__ __forceinline__ void gload_lds16(const void* g, void* l) {
    __builtin_amdgcn_global_load_lds(
        (const __attribute__((address_space(1))) unsigned int*)g,
        (__attribute__((address_space(3))) unsigned int*)l, 16, 0, 0);
}

// ---------------- fp32 -> fp16 conversion ------------------------------------
__global__ __launch_bounds__(256) void convert_kernel(
    const float* __restrict__ x,
    const float* __restrict__ wq, const float* __restrict__ wk, const float* __restrict__ wv,
    f16* __restrict__ x_h, f16* __restrict__ wq_h, f16* __restrict__ wk_h, f16* __restrict__ wv_h)
{
    const int NX = Bq*Lq*Dq;        // 4194304
    const int NW = Dq*Dq;           // 1048576
    const int total4 = (NX + 3*NW) / 4;
    for (int i = blockIdx.x*blockDim.x + threadIdx.x; i < total4;
         i += gridDim.x*blockDim.x) {
        int e = i * 4;
        const float* src; f16* dst; int off;
        if (e < NX) { src = x; dst = x_h; off = e; }
        else {
            int t = e - NX; int w = t >> 20; off = t & (NW-1);
            src = (w==0) ? wq : (w==1) ? wk : wv;
            dst = (w==0) ? wq_h : (w==1) ? wk_h : wv_h;
        }
        float4 v = *reinterpret_cast<const float4*>(src + off);
        f16x4 hv; hv.x=(f16)v.x; hv.y=(f16)v.y; hv.z=(f16)v.z; hv.w=(f16)v.w;
        *reinterpret_cast<f16x4*>(dst + off) = hv;
    }
}

// ---------------- QKV projection, fp16 MFMA ----------------------------------
// C[m,n] = sum_k X[m,k] * W[n,k];  M=4096, N=1024, K=1024, z selects W
#define GBM 128
#define GBN 128
#define GBK 32

__global__ __launch_bounds__(256) void qkv_mfma_kernel(
    const f16* __restrict__ x_h,
    const f16* __restrict__ wq_h, const f16* __restrict__ wk_h, const f16* __restrict__ wv_h,
    f16* __restrict__ q_h, f16* __restrict__ k_h, f16* __restrict__ vT_h)
{
    __shared__ __align__(16) f16 As[GBM*GBK];   // [m][k], 64B rows -> conflict-free b128
    __shared__ __align__(16) f16 Bs[GBN*GBK];   // [n][k]

    const int tid  = threadIdx.x;
    const int lane = tid & 63;
    const int wave = tid >> 6;
    const int wr = wave >> 1, wc = wave & 1;
    const int l15 = lane & 15, l4 = lane >> 4;
    const int n0 = blockIdx.x * GBN;
    const int m0 = blockIdx.y * GBM;
    const int z  = blockIdx.z;
    const f16* W = (z==0) ? wq_h : (z==1) ? wk_h : wv_h;

    const int sslot = tid & 3;     // 16B slot within a 64B k-row

    f32x4 acc[4][4];
    #pragma unroll
    for (int i=0;i<4;++i)
        #pragma unroll
        for (int j=0;j<4;++j) acc[i][j] = f32x4{0.f,0.f,0.f,0.f};

    for (int kt = 0; kt < Dq; kt += GBK) {
        __syncthreads();
        #pragma unroll
        for (int j = 0; j < 2; ++j) {
            int slotIdx = tid + j*256;
            int row = slotIdx >> 2;            // 0..127
            gload_lds16(x_h + (size_t)(m0+row)*Dq + kt + sslot*8,
                        (char*)As + slotIdx*16);
            gload_lds16(W   + (size_t)(n0+row)*Dq + kt + sslot*8,
                        (char*)Bs + slotIdx*16);
        }
        __syncthreads();

        f16x8 a[4], b[4];
        #pragma unroll
        for (int m=0;m<4;++m) {
            int row = wr*64 + m*16 + l15;
            a[m] = *reinterpret_cast<const f16x8*>((const char*)As + row*64 + l4*16);
        }
        #pragma unroll
        for (int n=0;n<4;++n) {
            int row = wc*64 + n*16 + l15;
            b[n] = *reinterpret_cast<const f16x8*>((const char*)Bs + row*64 + l4*16);
        }
        #pragma unroll
        for (int m=0;m<4;++m)
            #pragma unroll
            for (int n=0;n<4;++n)
                acc[m][n] = __builtin_amdgcn_mfma_f32_16x16x32_f16(a[m], b[n], acc[m][n], 0,0,0);
    }

    // epilogue: q,k row-major [bh][l][d]; v transposed [bh][d][l]
    #pragma unroll
    for (int m=0;m<4;++m) {
        #pragma unroll
        for (int r=0;r<4;++r) {
            int grow = m0 + wr*64 + m*16 + l4*4 + r;
            int b_   = grow >> 11;
            int lrow = grow & (Lq-1);
            #pragma unroll
            for (int n=0;n<4;++n) {
                int gcol = n0 + wc*64 + n*16 + l15;
                int h = gcol >> 6, d = gcol & 63;
                int bh = b_*Hq + h;
                f16 val = (f16)acc[m][n][r];
                if (z==0)      q_h[((size_t)bh*Lq + lrow)*HDq + d] = val;
                else if (z==1) k_h[((size_t)bh*Lq + lrow)*HDq + d] = val;
                else           vT_h[((size_t)bh*HDq + d)*Lq + lrow] = val;
            }
        }
    }
}

// ---------------- flash attention, fp16 MFMA ---------------------------------
// 512 threads = 8 waves; wave owns 16 q-rows; KBLK=64 staged in swizzled LDS
__global__ __launch_bounds__(512) void attn_mfma_kernel(
    const f16* __restrict__ q_h, const f16* __restrict__ k_h, const f16* __restrict__ vT_h,
    const float* __restrict__ quantum, const float* __restrict__ scale,
    float* __restrict__ out)
{
    __shared__ __align__(16) unsigned short Ks[64*64];    // swizzled [key][d]
    __shared__ __align__(16) unsigned short VTs[64*64];   // swizzled [d][key]
    __shared__ __align__(16) unsigned short Ps[8][16*64]; // per-wave P, swizzled [row][key]

    const int tid  = threadIdx.x;
    const int lane = tid & 63;
    const int wave = tid >> 6;
    const int l15 = lane & 15, l4 = lane >> 4;
    const int bh = blockIdx.y;
    const int b_ = bh >> 4, h = bh & 15;
    const int q0 = blockIdx.x*128 + wave*16;     // this wave's q base
    const float sc = scale[h];

    // Q fragments (ks=0,1), held in registers for the whole loop
    f16x8 qf[2];
    #pragma unroll
    for (int ks=0; ks<2; ++ks)
        qf[ks] = *reinterpret_cast<const f16x8*>(
            q_h + ((size_t)bh*Lq + q0 + l15)*HDq + ks*32 + l4*8);

    f32x4 acc_o[4];           // [d-tile]; rows via regs (row = l4*4+r)
    float m_r[4], s_r[4];
    #pragma unroll
    for (int dt=0;dt<4;++dt) acc_o[dt] = f32x4{0.f,0.f,0.f,0.f};
    #pragma unroll
    for (int r=0;r<4;++r) { m_r[r] = -1e30f; s_r[r] = 0.f; }

    const int sj = tid >> 3;                 // staging row 0..63
    const int ss = tid & 7;                  // linear 16B slot
    const int swz_s = ss ^ (sj & 7);         // swizzled source slot

    for (int k0 = 0; k0 < Lq; k0 += 64) {
        __syncthreads();
        gload_lds16(k_h  + ((size_t)bh*Lq + k0 + sj)*HDq + swz_s*8,
                    (char*)Ks + tid*16);
        gload_lds16(vT_h + ((size_t)(bh*HDq + sj))*Lq + k0 + swz_s*8,
                    (char*)VTs + tid*16);
        __syncthreads();

        // S = Q K^T over 4 key-tiles
        f32x4 s_acc[4];
        #pragma unroll
        for (int kt=0;kt<4;++kt) {
            s_acc[kt] = f32x4{0.f,0.f,0.f,0.f};
            #pragma unroll
            for (int ks=0;ks<2;++ks) {
                int row = kt*16 + l15;
                f16x8 kf = *reinterpret_cast<const f16x8*>(
                    (const char*)Ks + row*128 + ((ks*4 + l4) ^ (row&7))*16);
                s_acc[kt] = __builtin_amdgcn_mfma_f32_16x16x32_f16(qf[ks], kf, s_acc[kt], 0,0,0);
            }
        }

        // online softmax; lane owns rows l4*4+r (replicated across the 16-lane group)
        #pragma unroll
        for (int r=0;r<4;++r) {
            int qrow = l4*4 + r;
            float lg[4];
            #pragma unroll
            for (int kt=0;kt<4;++kt) {
                float qv = quantum[(size_t)b_*Lq*Lq + (size_t)(q0 + qrow)*Lq + k0 + kt*16 + l15];
                lg[kt] = fmaf(s_acc[kt][r], 0.125f, qv) * sc;
            }
            float mx = fmaxf(fmaxf(lg[0],lg[1]), fmaxf(lg[2],lg[3]));
            #pragma unroll
            for (int off=1; off<16; off<<=1) mx = fmaxf(mx, __shfl_xor(mx, off));
            float newm = fmaxf(m_r[r], mx);
            float p0 = __expf(lg[0]-newm), p1 = __expf(lg[1]-newm);
            float p2 = __expf(lg[2]-newm), p3 = __expf(lg[3]-newm);
            float corr = __expf(m_r[r]-newm);
            float ps = p0+p1+p2+p3;
            #pragma unroll
            for (int off=1; off<16; off<<=1) ps += __shfl_xor(ps, off);
            s_r[r] = s_r[r]*corr + ps;
            m_r[r] = newm;
            #pragma unroll
            for (int dt=0;dt<4;++dt) acc_o[dt][r] *= corr;

            float pv[4] = {p0,p1,p2,p3};
            #pragma unroll
            for (int kt=0;kt<4;++kt) {
                int key = kt*16 + l15;
                int slot = key >> 3;
                int byteoff = qrow*128 + ((slot ^ (qrow&7))*16) + (key&7)*2;
                f16 ph = (f16)pv[kt];
                *(unsigned short*)((char*)Ps[wave] + byteoff) =
                    __builtin_bit_cast(unsigned short, ph);
            }
        }
        // make this wave's P writes visible to its own cross-lane reads
        asm volatile("s_waitcnt lgkmcnt(0)" ::: "memory");
        __builtin_amdgcn_sched_barrier(0);

        // P fragments (A-operand layout)
        f16x8 pf[2];
        #pragma unroll
        for (int ks=0;ks<2;++ks) {
            int row = l15;
            pf[ks] = *reinterpret_cast<const f16x8*>(
                (const char*)Ps[wave] + row*128 + ((ks*4 + l4) ^ (row&7))*16);
        }
        // O += P V over 4 d-tiles
        #pragma unroll
        for (int dt=0;dt<4;++dt) {
            #pragma unroll
            for (int ks=0;ks<2;++ks) {
                int row = dt*16 + l15;
                f16x8 vf = *reinterpret_cast<const f16x8*>(
                    (const char*)VTs + row*128 + ((ks*4 + l4) ^ (row&7))*16);
                acc_o[dt] = __builtin_amdgcn_mfma_f32_16x16x32_f16(pf[ks], vf, acc_o[dt], 0,0,0);
            }
        }
    }

    #pragma unroll
    for (int dt=0;dt<4;++dt) {
        #pragma unroll
        for (int r=0;r<4;++r) {
            int qrow = l4*4 + r;
            out[((size_t)b_*Lq + q0 + qrow)*Dq + h*HDq + dt*16 + l15] = acc_o[dt][r] / s_r[r];
        }
    }
}

extern "C" void kernel_launch(void* const* d_in, const int* in_sizes, int n_in,
                              void* d_out, int out_size, void* d_ws, size_t ws_size,
                              hipStream_t stream) {
    const float* x       = (const float*)d_in[0];
    const float* quantum = (const float*)d_in[1];
    const float* wq      = (const float*)d_in[2];
    const float* wk      = (const float*)d_in[3];
    const float* wv      = (const float*)d_in[4];
    const float* scale   = (const float*)d_in[5];
    float* out = (float*)d_out;

    f16* ws   = (f16*)d_ws;
    f16* x_h  = ws;                    // 4,194,304
    f16* wq_h = ws + 4194304;          // 1,048,576
    f16* wk_h = ws + 5242880;
    f16* wv_h = ws + 6291456;
    f16* q_h  = ws + 7340032;          // 4,194,304
    f16* k_h  = ws + 11534336;
    f16* vT_h = ws + 15728640;         // total 19,922,944 f16 = 39.8 MB

    convert_kernel<<<1024, 256, 0, stream>>>(x, wq, wk, wv, x_h, wq_h, wk_h, wv_h);

    dim3 g1(Dq/GBN, (Bq*Lq)/GBM, 3);
    qkv_mfma_kernel<<<g1, 256, 0, stream>>>(x_h, wq_h, wk_h, wv_h, q_h, k_h, vT_h);

    dim3 g2(Lq/128, Bq*Hq);
    attn_mfma_kernel<<<g2, 512, 0, stream>>>(q_h, k_h, vT_h, quantum, scale, out);
}